// Round 5
// baseline (361.697 us; speedup 1.0000x reference)
//
#include <hip/hip_runtime.h>
#include <stdint.h>

#define DM 1024
#define DFF 4096
#define NH 16
#define DH 64
#define SEQ 2048
#define MROWS 4096  // B*S

typedef unsigned short u16;
typedef __attribute__((ext_vector_type(8))) short bf16x8;
typedef __attribute__((ext_vector_type(4))) float f32x4;
typedef __attribute__((ext_vector_type(4))) unsigned short u16x4;

__device__ __forceinline__ u16 f2b(float f) {
  union { float f; uint32_t u; } v; v.f = f;
  uint32_t r = v.u + 0x7FFFu + ((v.u >> 16) & 1u);
  return (u16)(r >> 16);
}

__device__ __forceinline__ void gl_lds16(const void* g, void* l) {
  __builtin_amdgcn_global_load_lds(
      (const __attribute__((address_space(1))) uint32_t*)g,
      (__attribute__((address_space(3))) uint32_t*)l, 16, 0, 0);
}

// ---------------- weight fp32 -> bf16 convert (all 6 weights, one kernel) --
struct CvtArgs { const float* src[6]; u16* dst[6]; int n4[6]; };

__global__ void cvt_kernel(CvtArgs a) {
  const int stride = gridDim.x * blockDim.x;
  const int t0 = blockIdx.x * blockDim.x + threadIdx.x;
  for (int i = 0; i < 6; ++i) {
    const float4* s = (const float4*)a.src[i];
    u16x4* d = (u16x4*)a.dst[i];
    const int n = a.n4[i];
    for (int idx = t0; idx < n; idx += stride) {
      float4 v = s[idx];
      u16x4 o;
      o[0] = f2b(v.x); o[1] = f2b(v.y); o[2] = f2b(v.z); o[3] = f2b(v.w);
      d[idx] = o;
    }
  }
}

// ---------------- fused LayerNorm: fp32 in -> bf16 out ---------------------
__global__ __launch_bounds__(256)
void ln_kernel(const float* __restrict__ x, const float* __restrict__ g,
               const float* __restrict__ be, u16* __restrict__ out) {
  const int row = blockIdx.x;
  const int tid = threadIdx.x;
  const float4 v = ((const float4*)(x + (size_t)row * DM))[tid];
  float s  = v.x + v.y + v.z + v.w;
  float s2 = v.x * v.x + v.y * v.y + v.z * v.z + v.w * v.w;
  #pragma unroll
  for (int m = 1; m < 64; m <<= 1) {
    s  += __shfl_xor(s,  m, 64);
    s2 += __shfl_xor(s2, m, 64);
  }
  __shared__ float red[8];
  const int w = tid >> 6, lane = tid & 63;
  if (lane == 0) { red[w] = s; red[4 + w] = s2; }
  __syncthreads();
  s  = red[0] + red[1] + red[2] + red[3];
  s2 = red[4] + red[5] + red[6] + red[7];
  const float mu  = s * (1.0f / DM);
  const float var = s2 * (1.0f / DM) - mu * mu;
  const float rstd = rsqrtf(var + 1e-5f);
  const float4 gv = ((const float4*)g)[tid];
  const float4 bv = ((const float4*)be)[tid];
  u16x4 o;
  o[0] = f2b((v.x - mu) * rstd * gv.x + bv.x);
  o[1] = f2b((v.y - mu) * rstd * gv.y + bv.y);
  o[2] = f2b((v.z - mu) * rstd * gv.z + bv.z);
  o[3] = f2b((v.w - mu) * rstd * gv.w + bv.w);
  ((u16x4*)(out + (size_t)row * DM))[tid] = o;
}

// ---------------- combine: out = p0 + p1 + bias + resid (fp32) -------------
__global__ __launch_bounds__(256)
void combine_kernel(const float4* __restrict__ p0, const float4* __restrict__ p1,
                    const float4* __restrict__ bias, const float4* __restrict__ resid,
                    float4* __restrict__ out, int total4, int colmask4) {
  for (int i = blockIdx.x * 256 + threadIdx.x; i < total4; i += gridDim.x * 256) {
    float4 a = p0[i], b = p1[i], bs = bias[i & colmask4], rr = resid[i];
    float4 o;
    o.x = a.x + b.x + bs.x + rr.x;
    o.y = a.y + b.y + bs.y + rr.y;
    o.z = a.z + b.z + bs.z + rr.z;
    o.w = a.w + b.w + bs.w + rr.w;
    out[i] = o;
  }
}

// ------- fused combine + LayerNorm: x1 = p0+p1+bias+resid (fp32 out),
//         norm = LN(x1)*g+b (bf16 out, separate buffer) ---------------------
__global__ __launch_bounds__(256)
void combine_ln_kernel(const float4* __restrict__ p0, const float4* __restrict__ p1,
                       const float4* __restrict__ bias, const float4* __restrict__ resid,
                       float4* __restrict__ xout,
                       const float* __restrict__ g, const float* __restrict__ be,
                       u16* __restrict__ nout) {
  const int row = blockIdx.x;
  const int tid = threadIdx.x;
  const int i = row * (DM / 4) + tid;
  const float4 a = p0[i], b = p1[i], bs = bias[tid], rr = resid[i];
  float4 v;
  v.x = a.x + b.x + bs.x + rr.x;
  v.y = a.y + b.y + bs.y + rr.y;
  v.z = a.z + b.z + bs.z + rr.z;
  v.w = a.w + b.w + bs.w + rr.w;
  xout[i] = v;
  float s  = v.x + v.y + v.z + v.w;
  float s2 = v.x * v.x + v.y * v.y + v.z * v.z + v.w * v.w;
  #pragma unroll
  for (int m = 1; m < 64; m <<= 1) {
    s  += __shfl_xor(s,  m, 64);
    s2 += __shfl_xor(s2, m, 64);
  }
  __shared__ float red[8];
  const int w = tid >> 6, lane = tid & 63;
  if (lane == 0) { red[w] = s; red[4 + w] = s2; }
  __syncthreads();
  s  = red[0] + red[1] + red[2] + red[3];
  s2 = red[4] + red[5] + red[6] + red[7];
  const float mu  = s * (1.0f / DM);
  const float var = s2 * (1.0f / DM) - mu * mu;
  const float rstd = rsqrtf(var + 1e-5f);
  const float4 gv = ((const float4*)g)[tid];
  const float4 bv = ((const float4*)be)[tid];
  u16x4 o;
  o[0] = f2b((v.x - mu) * rstd * gv.x + bv.x);
  o[1] = f2b((v.y - mu) * rstd * gv.y + bv.y);
  o[2] = f2b((v.z - mu) * rstd * gv.z + bv.z);
  o[3] = f2b((v.w - mu) * rstd * gv.w + bv.w);
  ((u16x4*)(nout + (size_t)row * DM))[tid] = o;
}

// ---------------- GEMM: C[M,N] = A[M,K](bf16) * W[N,K](bf16)^T + bias ------
// EPI 0: -> bf16 (z==2 + vtrans: write transposed [b*DM+col][SEQ];
//                 z==0 + vtrans: scale by 1/8 — Q head-dim scale folded in)
// EPI 1: +GELU(exact) -> bf16      EPI 2: +resid -> f32
// EPI 3: K-split partial, no bias -> f32 (z selects K-chunk + partial buffer)
struct GemmPtrs { const u16* W[3]; const float* bias[3]; void* out[3];
                  const float* resid; int vtrans; };

template<int EPI>
__global__ __launch_bounds__(256)
void gemm_bt(const u16* __restrict__ A, GemmPtrs p, int M, int N,
             int Kstride, int Kchunk) {
  __shared__ __align__(16) u16 As[128 * 64];
  __shared__ __align__(16) u16 Bs[128 * 64];
  const u16* __restrict__ Wm = p.W[blockIdx.z];
  const float* __restrict__ bias = p.bias[blockIdx.z];
  void* outv = p.out[blockIdx.z];
  const float* resid = p.resid;

  const int tid = threadIdx.x;
  const int lane = tid & 63;
  const int w = tid >> 6;
  const int brow = blockIdx.y * 128;
  const int bcol = blockIdx.x * 128;
  const int wr = (w >> 1) * 64, wc = (w & 1) * 64;
  const int koff = (EPI == 3) ? blockIdx.z * Kchunk : 0;

  f32x4 acc[4][4] = {};

  const int srow = lane >> 3;           // staging row within 8-row group
  const int scol = (lane & 7) * 8;      // staging col (bf16 elements)
  const int nkt = Kchunk >> 6;
  for (int kt = 0; kt < nkt; ++kt) {
    const int k0 = koff + kt * 64;
    #pragma unroll
    for (int i = 0; i < 4; ++i) {
      const int r = i * 32 + w * 8;
      gl_lds16(&A [(size_t)(brow + r + srow) * Kstride + k0 + scol], &As[r * 64]);
      gl_lds16(&Wm[(size_t)(bcol + r + srow) * Kstride + k0 + scol], &Bs[r * 64]);
    }
    __syncthreads();
    #pragma unroll
    for (int ks = 0; ks < 2; ++ks) {
      const int ko = ks * 32 + (lane >> 4) * 8;
      bf16x8 a[4], b[4];
      #pragma unroll
      for (int f = 0; f < 4; ++f)
        a[f] = *(const bf16x8*)&As[(wr + f * 16 + (lane & 15)) * 64 + ko];
      #pragma unroll
      for (int f = 0; f < 4; ++f)
        b[f] = *(const bf16x8*)&Bs[(wc + f * 16 + (lane & 15)) * 64 + ko];
      #pragma unroll
      for (int fr = 0; fr < 4; ++fr)
        #pragma unroll
        for (int fc = 0; fc < 4; ++fc)
          acc[fr][fc] = __builtin_amdgcn_mfma_f32_16x16x32_bf16(a[fr], b[fc], acc[fr][fc], 0, 0, 0);
    }
    __syncthreads();
  }

  const int orow0 = brow + wr + (lane >> 4) * 4;
  const int ocol0 = bcol + wc + (lane & 15);

  if (EPI == 0 && p.vtrans && blockIdx.z == 2) {
    // V projection written transposed: Vt[(b*DM + col)][s], s = row % SEQ
    #pragma unroll
    for (int fr = 0; fr < 4; ++fr) {
      const int row0 = orow0 + fr * 16;
      const int bq = row0 >> 11, s0 = row0 & (SEQ - 1);
      #pragma unroll
      for (int fc = 0; fc < 4; ++fc) {
        const int col = ocol0 + fc * 16;
        const float bvv = bias[col];
        u16x4 o;
        #pragma unroll
        for (int r = 0; r < 4; ++r) o[r] = f2b(acc[fr][fc][r] + bvv);
        *(u16x4*)((u16*)outv + (size_t)(bq * DM + col) * SEQ + s0) = o;
      }
    }
    return;
  }

  const float oscale = (EPI == 0 && p.vtrans && blockIdx.z == 0) ? 0.125f : 1.0f;

  #pragma unroll
  for (int fr = 0; fr < 4; ++fr) {
    #pragma unroll
    for (int fc = 0; fc < 4; ++fc) {
      const int col = ocol0 + fc * 16;
      const float bvv = (EPI == 3) ? 0.0f : bias[col];
      #pragma unroll
      for (int r = 0; r < 4; ++r) {
        const int row = orow0 + fr * 16 + r;
        const size_t idx = (size_t)row * N + col;
        float v = acc[fr][fc][r] + bvv;
        if (EPI == 0) {
          ((u16*)outv)[idx] = f2b(v * oscale);
        } else if (EPI == 1) {
          float ge = 0.5f * v * (1.0f + erff(v * 0.70710678118654752f));
          ((u16*)outv)[idx] = f2b(ge);
        } else if (EPI == 2) {
          ((float*)outv)[idx] = v + resid[idx];
        } else {
          ((float*)outv)[idx] = v;   // partial, bias added in combine
        }
      }
    }
  }
}

// ---------------- flash attention: Q,K [B,S,H*DH]; Vt [(b*DM+h*DH+d)][s] ---
// Q pre-scaled by 1/8 in the QKV GEMM epilogue.
// Single-buffered K/V staging (TLP at ~4 blocks/CU hides the stage stall;
// round-3 double-buffer cut occupancy 36->24% and regressed — m132 pattern).
// LDS tiles XOR-swizzled via pre-swizzled global source (rule #21).
// Softmax: defer-max (THR=8), per-lane partial row-sum reduced once at end.
__global__ __launch_bounds__(256)
void attn_kernel(const u16* __restrict__ Q, const u16* __restrict__ K,
                 const u16* __restrict__ Vt, u16* __restrict__ O) {
  __shared__ __align__(16) u16 Ks[64 * 64];
  __shared__ __align__(16) u16 Vts[64 * 64];   // [d][key]
  __shared__ __align__(16) u16 Ps[4][16 * 64]; // per-wave P tile, swizzled
  const int tid = threadIdx.x, lane = tid & 63, w = tid >> 6;
  const int bh = blockIdx.y, b = bh >> 4, h = bh & 15;
  const int q0 = blockIdx.x * 64 + w * 16;     // wave's q-row base in seq
  const size_t base = (size_t)b * SEQ * DM + (size_t)h * DH;
  const size_t vbase = (size_t)(b * DM + h * DH) * SEQ;  // Vt row-major [d][s]

  const int l15 = lane & 15, hi = lane >> 4, l7 = lane & 7;
  const int kf[2] = { (hi ^ l7) * 8, ((4 + hi) ^ l7) * 8 };

  // Q fragments (A-layout): row = l15, k = ks*32 + hi*8
  bf16x8 qf[2];
  {
    const size_t qrow = base + (size_t)(q0 + l15) * DM;
    #pragma unroll
    for (int ks = 0; ks < 2; ++ks)
      qf[ks] = *(const bf16x8*)&Q[qrow + ks * 32 + hi * 8];
  }

  f32x4 oacc[4] = {};
  float mrow[4], lpart[4];
  #pragma unroll
  for (int r = 0; r < 4; ++r) { mrow[r] = -1e30f; lpart[r] = 0.0f; }

  const int srow = lane >> 3;
  const int scol_sw = ((lane & 7) ^ srow) * 8;   // inverse-swizzled global chunk

  for (int kt = 0; kt < SEQ / 64; ++kt) {
    // stage K tile and Vt tile (swizzled via pre-swizzled source)
    #pragma unroll
    for (int i = 0; i < 2; ++i) {
      const int r = i * 32 + w * 8;
      gl_lds16(&K[base + (size_t)(kt * 64 + r + srow) * DM + scol_sw], &Ks[r * 64]);
      gl_lds16(&Vt[vbase + (size_t)(r + srow) * SEQ + kt * 64 + scol_sw], &Vts[r * 64]);
    }
    __syncthreads();

    // S = Q K^T (Q pre-scaled)
    f32x4 sacc[4] = {};
    __builtin_amdgcn_s_setprio(1);
    #pragma unroll
    for (int ks = 0; ks < 2; ++ks) {
      #pragma unroll
      for (int fn = 0; fn < 4; ++fn) {
        bf16x8 kb = *(const bf16x8*)&Ks[(fn * 16 + l15) * 64 + kf[ks]];
        sacc[fn] = __builtin_amdgcn_mfma_f32_16x16x32_bf16(qf[ks], kb, sacc[fn], 0, 0, 0);
      }
    }
    __builtin_amdgcn_s_setprio(0);

    // online softmax: defer-max + per-lane partial sums
    #pragma unroll
    for (int r = 0; r < 4; ++r) {
      float tm = fmaxf(fmaxf(sacc[0][r], sacc[1][r]), fmaxf(sacc[2][r], sacc[3][r]));
      #pragma unroll
      for (int m = 1; m <= 8; m <<= 1) tm = fmaxf(tm, __shfl_xor(tm, m, 64));
      if (__any(tm > mrow[r] + 8.0f)) {
        const float mnew = fmaxf(mrow[r], tm);
        const float fs = __expf(mrow[r] - mnew);
        mrow[r] = mnew;
        lpart[r] *= fs;
        #pragma unroll
        for (int fd = 0; fd < 4; ++fd) oacc[fd][r] *= fs;
      }
      float ps = 0.0f;
      #pragma unroll
      for (int fn = 0; fn < 4; ++fn) {
        float pp = __expf(sacc[fn][r] - mrow[r]);
        sacc[fn][r] = pp;
        ps += pp;
      }
      lpart[r] += ps;
    }

    // spill P (C-layout: q=(hi*4+r), k=fn*16+l15) to LDS, swizzled
    {
      const int pr = hi * 4;
      #pragma unroll
      for (int fn = 0; fn < 4; ++fn)
        #pragma unroll
        for (int r = 0; r < 4; ++r) {
          const int q = pr + r;
          Ps[w][q * 64 + ((fn * 16 + l15) ^ ((q & 7) << 3))] = f2b(sacc[fn][r]);
        }
    }
    __builtin_amdgcn_s_setprio(1);
    #pragma unroll
    for (int ks = 0; ks < 2; ++ks) {
      bf16x8 pa = *(const bf16x8*)&Ps[w][l15 * 64 + kf[ks]];
      #pragma unroll
      for (int fd = 0; fd < 4; ++fd) {
        bf16x8 vbf = *(const bf16x8*)&Vts[(fd * 16 + l15) * 64 + kf[ks]];
        oacc[fd] = __builtin_amdgcn_mfma_f32_16x16x32_bf16(pa, vbf, oacc[fd], 0, 0, 0);
      }
    }
    __builtin_amdgcn_s_setprio(0);
    __syncthreads();
  }

  // final row-sum reduction (once, not per tile)
  #pragma unroll
  for (int r = 0; r < 4; ++r) {
    #pragma unroll
    for (int m = 1; m <= 8; m <<= 1) lpart[r] += __shfl_xor(lpart[r], m, 64);
  }

  #pragma unroll
  for (int fd = 0; fd < 4; ++fd)
    #pragma unroll
    for (int r = 0; r < 4; ++r) {
      const int row = q0 + hi * 4 + r;
      const float v = oacc[fd][r] / lpart[r];
      O[base + (size_t)row * DM + fd * 16 + l15] = f2b(v);
    }
}

// ---------------------------------------------------------------------------
extern "C" void kernel_launch(void* const* d_in, const int* in_sizes, int n_in,
                              void* d_out, int out_size, void* d_ws, size_t ws_size,
                              hipStream_t stream) {
  const float* x    = (const float*)d_in[0];
  const float* Wq   = (const float*)d_in[1];
  const float* bq   = (const float*)d_in[2];
  const float* Wk   = (const float*)d_in[3];
  const float* bk   = (const float*)d_in[4];
  const float* Wv   = (const float*)d_in[5];
  const float* bv   = (const float*)d_in[6];
  const float* Wo   = (const float*)d_in[7];
  const float* bo   = (const float*)d_in[8];
  const float* ln1g = (const float*)d_in[9];
  const float* ln1b = (const float*)d_in[10];
  const float* W1   = (const float*)d_in[11];
  const float* b1   = (const float*)d_in[12];
  const float* W2   = (const float*)d_in[13];
  const float* b2   = (const float*)d_in[14];
  const float* ln2g = (const float*)d_in[15];
  const float* ln2b = (const float*)d_in[16];
  float* out = (float*)d_out;

  char* wsb = (char*)d_ws;
  size_t off = 0;
  auto alloc = [&](size_t bytes) -> char* {
    char* pp = wsb + off;
    off += (bytes + 255) & ~(size_t)255;
    return pp;
  };
  u16* Wq_b = (u16*)alloc((size_t)DM * DM * 2);
  u16* Wk_b = (u16*)alloc((size_t)DM * DM * 2);
  u16* Wv_b = (u16*)alloc((size_t)DM * DM * 2);
  u16* Wo_b = (u16*)alloc((size_t)DM * DM * 2);
  u16* W1_b = (u16*)alloc((size_t)DFF * DM * 2);
  u16* W2_b = (u16*)alloc((size_t)DM * DFF * 2);
  u16* xn   = (u16*)alloc((size_t)MROWS * DM * 2);
  u16* qb   = (u16*)alloc((size_t)MROWS * DM * 2);
  u16* kb   = (u16*)alloc((size_t)MROWS * DM * 2);
  u16* vt   = (u16*)alloc((size_t)MROWS * DM * 2);  // transposed V
  u16* ao   = (u16*)alloc((size_t)MROWS * DM * 2);  // attn out, then LN2 out
  u16* h1   = (u16*)alloc((size_t)MROWS * DFF * 2);

  // K-split partial buffers (fp32, 16 MB each) reuse dead regions:
  // pA = xn∪qb, pB = kb∪vt — dead during O-proj (after attn) and FFN2.
  float* pA = (float*)xn;
  float* pB = (float*)kb;

  // 1. convert weights to bf16
  CvtArgs ca;
  ca.src[0] = Wq; ca.dst[0] = Wq_b; ca.n4[0] = DM * DM / 4;
  ca.src[1] = Wk; ca.dst[1] = Wk_b; ca.n4[1] = DM * DM / 4;
  ca.src[2] = Wv; ca.dst[2] = Wv_b; ca.n4[2] = DM * DM / 4;
  ca.src[3] = Wo; ca.dst[3] = Wo_b; ca.n4[3] = DM * DM / 4;
  ca.src[4] = W1; ca.dst[4] = W1_b; ca.n4[4] = DFF * DM / 4;
  ca.src[5] = W2; ca.dst[5] = W2_b; ca.n4[5] = DM * DFF / 4;
  cvt_kernel<<<2048, 256, 0, stream>>>(ca);

  // 2. LN1
  ln_kernel<<<MROWS, 256, 0, stream>>>(x, ln1g, ln1b, xn);

  // 3. QKV projections (z-fused; V transposed; Q pre-scaled by 1/8)
  GemmPtrs pq = {};
  pq.W[0] = Wq_b; pq.W[1] = Wk_b; pq.W[2] = Wv_b;
  pq.bias[0] = bq; pq.bias[1] = bk; pq.bias[2] = bv;
  pq.out[0] = qb; pq.out[1] = kb; pq.out[2] = vt;
  pq.vtrans = 1;
  gemm_bt<0><<<dim3(DM / 128, MROWS / 128, 3), 256, 0, stream>>>(xn, pq, MROWS, DM, DM, DM);

  // 4. attention
  attn_kernel<<<dim3(SEQ / 64, 2 * NH), 256, 0, stream>>>(qb, kb, vt, ao);

  // 5. output projection, K-split x2 -> partials; fused combine+bias+x+LN2
  GemmPtrs po = {};
  po.W[0] = Wo_b; po.W[1] = Wo_b;
  po.bias[0] = bo; po.bias[1] = bo;
  po.out[0] = pA; po.out[1] = pB;
  gemm_bt<3><<<dim3(DM / 128, MROWS / 128, 2), 256, 0, stream>>>(ao, po, MROWS, DM, DM, DM / 2);
  combine_ln_kernel<<<MROWS, 256, 0, stream>>>((const float4*)pA, (const float4*)pB,
                                               (const float4*)bo, (const float4*)x,
                                               (float4*)out, ln2g, ln2b, ao);

  // 6. FFN up + GELU (input: LN2 output in ao)
  GemmPtrs p1 = {};
  p1.W[0] = W1_b; p1.bias[0] = b1; p1.out[0] = h1;
  gemm_bt<1><<<dim3(DFF / 128, MROWS / 128, 1), 256, 0, stream>>>(ao, p1, MROWS, DFF, DM, DM);

  // 7. FFN down, K-split x2 -> partials, then combine(+bias+resid in place)
  GemmPtrs p2 = {};
  p2.W[0] = W2_b; p2.W[1] = W2_b;
  p2.bias[0] = b2; p2.bias[1] = b2;
  p2.out[0] = pA; p2.out[1] = pB;
  gemm_bt<3><<<dim3(DM / 128, MROWS / 128, 2), 256, 0, stream>>>(h1, p2, MROWS, DM, DFF, DFF / 2);
  combine_kernel<<<2048, 256, 0, stream>>>((const float4*)pA, (const float4*)pB,
                                           (const float4*)b2, (const float4*)out,
                                           (float4*)out, MROWS * DM / 4, DM / 4 - 1);
}

// Round 6
// 317.174 us; speedup vs baseline: 1.1404x; 1.1404x over previous
//
#include <hip/hip_runtime.h>
#include <hip/hip_bf16.h>
#include <stdint.h>

#define DM 1024
#define DFF 4096
#define NH 16
#define DH 64
#define SEQ 2048
#define MROWS 4096  // B*S

typedef unsigned short u16;
typedef __attribute__((ext_vector_type(8))) short bf16x8;
typedef __attribute__((ext_vector_type(4))) float f32x4;
typedef __attribute__((ext_vector_type(4))) unsigned short u16x4;

__device__ __forceinline__ u16 f2b(float f) {
  union { float f; uint32_t u; } v; v.f = f;
  uint32_t r = v.u + 0x7FFFu + ((v.u >> 16) & 1u);
  return (u16)(r >> 16);
}

// native convert — clang emits v_cvt_pk_bf16_f32 for pairs (RNE)
__device__ __forceinline__ u16 f2bn(float f) {
  __hip_bfloat16 h = __float2bfloat16(f);
  return *reinterpret_cast<u16*>(&h);
}

__device__ __forceinline__ void gl_lds16(const void* g, void* l) {
  __builtin_amdgcn_global_load_lds(
      (const __attribute__((address_space(1))) uint32_t*)g,
      (__attribute__((address_space(3))) uint32_t*)l, 16, 0, 0);
}

// ---------------- weight fp32 -> bf16 convert (all 6 weights, one kernel) --
struct CvtArgs { const float* src[6]; u16* dst[6]; int n4[6]; };

__global__ void cvt_kernel(CvtArgs a) {
  const int stride = gridDim.x * blockDim.x;
  const int t0 = blockIdx.x * blockDim.x + threadIdx.x;
  for (int i = 0; i < 6; ++i) {
    const float4* s = (const float4*)a.src[i];
    u16x4* d = (u16x4*)a.dst[i];
    const int n = a.n4[i];
    for (int idx = t0; idx < n; idx += stride) {
      float4 v = s[idx];
      u16x4 o;
      o[0] = f2b(v.x); o[1] = f2b(v.y); o[2] = f2b(v.z); o[3] = f2b(v.w);
      d[idx] = o;
    }
  }
}

// ---------------- fused LayerNorm: fp32 in -> bf16 out ---------------------
__global__ __launch_bounds__(256)
void ln_kernel(const float* __restrict__ x, const float* __restrict__ g,
               const float* __restrict__ be, u16* __restrict__ out) {
  const int row = blockIdx.x;
  const int tid = threadIdx.x;
  const float4 v = ((const float4*)(x + (size_t)row * DM))[tid];
  float s  = v.x + v.y + v.z + v.w;
  float s2 = v.x * v.x + v.y * v.y + v.z * v.z + v.w * v.w;
  #pragma unroll
  for (int m = 1; m < 64; m <<= 1) {
    s  += __shfl_xor(s,  m, 64);
    s2 += __shfl_xor(s2, m, 64);
  }
  __shared__ float red[8];
  const int w = tid >> 6, lane = tid & 63;
  if (lane == 0) { red[w] = s; red[4 + w] = s2; }
  __syncthreads();
  s  = red[0] + red[1] + red[2] + red[3];
  s2 = red[4] + red[5] + red[6] + red[7];
  const float mu  = s * (1.0f / DM);
  const float var = s2 * (1.0f / DM) - mu * mu;
  const float rstd = rsqrtf(var + 1e-5f);
  const float4 gv = ((const float4*)g)[tid];
  const float4 bv = ((const float4*)be)[tid];
  u16x4 o;
  o[0] = f2b((v.x - mu) * rstd * gv.x + bv.x);
  o[1] = f2b((v.y - mu) * rstd * gv.y + bv.y);
  o[2] = f2b((v.z - mu) * rstd * gv.z + bv.z);
  o[3] = f2b((v.w - mu) * rstd * gv.w + bv.w);
  ((u16x4*)(out + (size_t)row * DM))[tid] = o;
}

// ---------------- combine: out = p0 + p1 + bias + resid (fp32) -------------
__global__ __launch_bounds__(256)
void combine_kernel(const float4* __restrict__ p0, const float4* __restrict__ p1,
                    const float4* __restrict__ bias, const float4* __restrict__ resid,
                    float4* __restrict__ out, int total4, int colmask4) {
  for (int i = blockIdx.x * 256 + threadIdx.x; i < total4; i += gridDim.x * 256) {
    float4 a = p0[i], b = p1[i], bs = bias[i & colmask4], rr = resid[i];
    float4 o;
    o.x = a.x + b.x + bs.x + rr.x;
    o.y = a.y + b.y + bs.y + rr.y;
    o.z = a.z + b.z + bs.z + rr.z;
    o.w = a.w + b.w + bs.w + rr.w;
    out[i] = o;
  }
}

// ------- fused combine + LayerNorm: x1 = p0+p1+bias+resid (fp32 out),
//         norm = LN(x1)*g+b (bf16 out, separate buffer) ---------------------
__global__ __launch_bounds__(256)
void combine_ln_kernel(const float4* __restrict__ p0, const float4* __restrict__ p1,
                       const float4* __restrict__ bias, const float4* __restrict__ resid,
                       float4* __restrict__ xout,
                       const float* __restrict__ g, const float* __restrict__ be,
                       u16* __restrict__ nout) {
  const int row = blockIdx.x;
  const int tid = threadIdx.x;
  const int i = row * (DM / 4) + tid;
  const float4 a = p0[i], b = p1[i], bs = bias[tid], rr = resid[i];
  float4 v;
  v.x = a.x + b.x + bs.x + rr.x;
  v.y = a.y + b.y + bs.y + rr.y;
  v.z = a.z + b.z + bs.z + rr.z;
  v.w = a.w + b.w + bs.w + rr.w;
  xout[i] = v;
  float s  = v.x + v.y + v.z + v.w;
  float s2 = v.x * v.x + v.y * v.y + v.z * v.z + v.w * v.w;
  #pragma unroll
  for (int m = 1; m < 64; m <<= 1) {
    s  += __shfl_xor(s,  m, 64);
    s2 += __shfl_xor(s2, m, 64);
  }
  __shared__ float red[8];
  const int w = tid >> 6, lane = tid & 63;
  if (lane == 0) { red[w] = s; red[4 + w] = s2; }
  __syncthreads();
  s  = red[0] + red[1] + red[2] + red[3];
  s2 = red[4] + red[5] + red[6] + red[7];
  const float mu  = s * (1.0f / DM);
  const float var = s2 * (1.0f / DM) - mu * mu;
  const float rstd = rsqrtf(var + 1e-5f);
  const float4 gv = ((const float4*)g)[tid];
  const float4 bv = ((const float4*)be)[tid];
  u16x4 o;
  o[0] = f2b((v.x - mu) * rstd * gv.x + bv.x);
  o[1] = f2b((v.y - mu) * rstd * gv.y + bv.y);
  o[2] = f2b((v.z - mu) * rstd * gv.z + bv.z);
  o[3] = f2b((v.w - mu) * rstd * gv.w + bv.w);
  ((u16x4*)(nout + (size_t)row * DM))[tid] = o;
}

// ---------------- GEMM: C[M,N] = A[M,K](bf16) * W[N,K](bf16)^T + bias ------
// EPI 0: -> bf16 (z==2 + vtrans: write transposed [b*DM+col][SEQ];
//                 z==0 + vtrans: scale by 1/8 — Q head-dim scale folded in)
// EPI 1: +GELU(exact) -> bf16      EPI 2: +resid -> f32
// EPI 3: K-split partial, no bias -> f32 (z selects K-chunk + partial buffer)
struct GemmPtrs { const u16* W[3]; const float* bias[3]; void* out[3];
                  const float* resid; int vtrans; };

template<int EPI>
__global__ __launch_bounds__(256)
void gemm_bt(const u16* __restrict__ A, GemmPtrs p, int M, int N,
             int Kstride, int Kchunk) {
  __shared__ __align__(16) u16 As[128 * 64];
  __shared__ __align__(16) u16 Bs[128 * 64];
  const u16* __restrict__ Wm = p.W[blockIdx.z];
  const float* __restrict__ bias = p.bias[blockIdx.z];
  void* outv = p.out[blockIdx.z];
  const float* resid = p.resid;

  const int tid = threadIdx.x;
  const int lane = tid & 63;
  const int w = tid >> 6;
  const int brow = blockIdx.y * 128;
  const int bcol = blockIdx.x * 128;
  const int wr = (w >> 1) * 64, wc = (w & 1) * 64;
  const int koff = (EPI == 3) ? blockIdx.z * Kchunk : 0;

  f32x4 acc[4][4] = {};

  const int srow = lane >> 3;           // staging row within 8-row group
  const int scol = (lane & 7) * 8;      // staging col (bf16 elements)
  const int nkt = Kchunk >> 6;
  for (int kt = 0; kt < nkt; ++kt) {
    const int k0 = koff + kt * 64;
    #pragma unroll
    for (int i = 0; i < 4; ++i) {
      const int r = i * 32 + w * 8;
      gl_lds16(&A [(size_t)(brow + r + srow) * Kstride + k0 + scol], &As[r * 64]);
      gl_lds16(&Wm[(size_t)(bcol + r + srow) * Kstride + k0 + scol], &Bs[r * 64]);
    }
    __syncthreads();
    #pragma unroll
    for (int ks = 0; ks < 2; ++ks) {
      const int ko = ks * 32 + (lane >> 4) * 8;
      bf16x8 a[4], b[4];
      #pragma unroll
      for (int f = 0; f < 4; ++f)
        a[f] = *(const bf16x8*)&As[(wr + f * 16 + (lane & 15)) * 64 + ko];
      #pragma unroll
      for (int f = 0; f < 4; ++f)
        b[f] = *(const bf16x8*)&Bs[(wc + f * 16 + (lane & 15)) * 64 + ko];
      #pragma unroll
      for (int fr = 0; fr < 4; ++fr)
        #pragma unroll
        for (int fc = 0; fc < 4; ++fc)
          acc[fr][fc] = __builtin_amdgcn_mfma_f32_16x16x32_bf16(a[fr], b[fc], acc[fr][fc], 0, 0, 0);
    }
    __syncthreads();
  }

  const int orow0 = brow + wr + (lane >> 4) * 4;
  const int ocol0 = bcol + wc + (lane & 15);

  if (EPI == 0 && p.vtrans && blockIdx.z == 2) {
    // V projection written transposed: Vt[(b*DM + col)][s], s = row % SEQ
    #pragma unroll
    for (int fr = 0; fr < 4; ++fr) {
      const int row0 = orow0 + fr * 16;
      const int bq = row0 >> 11, s0 = row0 & (SEQ - 1);
      #pragma unroll
      for (int fc = 0; fc < 4; ++fc) {
        const int col = ocol0 + fc * 16;
        const float bvv = bias[col];
        u16x4 o;
        #pragma unroll
        for (int r = 0; r < 4; ++r) o[r] = f2b(acc[fr][fc][r] + bvv);
        *(u16x4*)((u16*)outv + (size_t)(bq * DM + col) * SEQ + s0) = o;
      }
    }
    return;
  }

  const float oscale = (EPI == 0 && p.vtrans && blockIdx.z == 0) ? 0.125f : 1.0f;

  #pragma unroll
  for (int fr = 0; fr < 4; ++fr) {
    #pragma unroll
    for (int fc = 0; fc < 4; ++fc) {
      const int col = ocol0 + fc * 16;
      const float bvv = (EPI == 3) ? 0.0f : bias[col];
      #pragma unroll
      for (int r = 0; r < 4; ++r) {
        const int row = orow0 + fr * 16 + r;
        const size_t idx = (size_t)row * N + col;
        float v = acc[fr][fc][r] + bvv;
        if (EPI == 0) {
          ((u16*)outv)[idx] = f2b(v * oscale);
        } else if (EPI == 1) {
          float ge = 0.5f * v * (1.0f + erff(v * 0.70710678118654752f));
          ((u16*)outv)[idx] = f2b(ge);
        } else if (EPI == 2) {
          ((float*)outv)[idx] = v + resid[idx];
        } else {
          ((float*)outv)[idx] = v;   // partial, bias added in combine
        }
      }
    }
  }
}

// ---------------- flash attention: Q,K [B,S,H*DH]; Vt [(b*DM+h*DH+d)][s] ---
// Q pre-scaled by 1/8 in the QKV GEMM epilogue.
// __launch_bounds__(256,4): forces total (VGPR+AGPR, unified file) <= 128
// per wave -> 4 blocks/CU. Round 3/4's 76-VGPR build totaled >128 -> 2
// blocks/CU (24% occ cap) and cost ~19us; reported VGPR_Count excludes AGPR.
// LDS tiles XOR-swizzled via pre-swizzled global source (rule #21).
// Softmax: defer-max (THR=8), per-lane partial row-sum reduced once at end.
__global__ __launch_bounds__(256, 4)
void attn_kernel(const u16* __restrict__ Q, const u16* __restrict__ K,
                 const u16* __restrict__ Vt, u16* __restrict__ O) {
  __shared__ __align__(16) u16 Ks[64 * 64];
  __shared__ __align__(16) u16 Vts[64 * 64];   // [d][key]
  __shared__ __align__(16) u16 Ps[4][16 * 64]; // per-wave P tile, swizzled
  const int tid = threadIdx.x, lane = tid & 63, w = tid >> 6;
  const int bh = blockIdx.y, b = bh >> 4, h = bh & 15;
  const int q0 = blockIdx.x * 64 + w * 16;     // wave's q-row base in seq
  const size_t base = (size_t)b * SEQ * DM + (size_t)h * DH;
  const size_t vbase = (size_t)(b * DM + h * DH) * SEQ;  // Vt row-major [d][s]

  const int l15 = lane & 15, hi = lane >> 4, l7 = lane & 7;
  const int kf[2] = { (hi ^ l7) * 8, ((4 + hi) ^ l7) * 8 };

  // Q fragments (A-layout): row = l15, k = ks*32 + hi*8
  bf16x8 qf[2];
  {
    const size_t qrow = base + (size_t)(q0 + l15) * DM;
    #pragma unroll
    for (int ks = 0; ks < 2; ++ks)
      qf[ks] = *(const bf16x8*)&Q[qrow + ks * 32 + hi * 8];
  }

  f32x4 oacc[4] = {};
  float mrow[4], lpart[4];
  #pragma unroll
  for (int r = 0; r < 4; ++r) { mrow[r] = -1e30f; lpart[r] = 0.0f; }

  const int srow = lane >> 3;
  const int scol_sw = ((lane & 7) ^ srow) * 8;   // inverse-swizzled global chunk

  for (int kt = 0; kt < SEQ / 64; ++kt) {
    // stage K tile and Vt tile (swizzled via pre-swizzled source)
    #pragma unroll
    for (int i = 0; i < 2; ++i) {
      const int r = i * 32 + w * 8;
      gl_lds16(&K[base + (size_t)(kt * 64 + r + srow) * DM + scol_sw], &Ks[r * 64]);
      gl_lds16(&Vt[vbase + (size_t)(r + srow) * SEQ + kt * 64 + scol_sw], &Vts[r * 64]);
    }
    __syncthreads();

    // S = Q K^T (Q pre-scaled)
    f32x4 sacc[4] = {};
    __builtin_amdgcn_s_setprio(1);
    #pragma unroll
    for (int ks = 0; ks < 2; ++ks) {
      #pragma unroll
      for (int fn = 0; fn < 4; ++fn) {
        bf16x8 kb = *(const bf16x8*)&Ks[(fn * 16 + l15) * 64 + kf[ks]];
        sacc[fn] = __builtin_amdgcn_mfma_f32_16x16x32_bf16(qf[ks], kb, sacc[fn], 0, 0, 0);
      }
    }
    __builtin_amdgcn_s_setprio(0);

    // online softmax: defer-max + per-lane partial sums
    #pragma unroll
    for (int r = 0; r < 4; ++r) {
      float tm = fmaxf(fmaxf(sacc[0][r], sacc[1][r]), fmaxf(sacc[2][r], sacc[3][r]));
      #pragma unroll
      for (int m = 1; m <= 8; m <<= 1) tm = fmaxf(tm, __shfl_xor(tm, m, 64));
      if (__any(tm > mrow[r] + 8.0f)) {
        const float mnew = fmaxf(mrow[r], tm);
        const float fs = __expf(mrow[r] - mnew);
        mrow[r] = mnew;
        lpart[r] *= fs;
        #pragma unroll
        for (int fd = 0; fd < 4; ++fd) oacc[fd][r] *= fs;
      }
      float ps = 0.0f;
      #pragma unroll
      for (int fn = 0; fn < 4; ++fn) {
        float pp = __expf(sacc[fn][r] - mrow[r]);
        sacc[fn][r] = pp;
        ps += pp;
      }
      lpart[r] += ps;
    }

    // spill P (C-layout: q=(hi*4+r), k=fn*16+l15) to LDS, swizzled
    {
      const int pr = hi * 4;
      #pragma unroll
      for (int fn = 0; fn < 4; ++fn)
        #pragma unroll
        for (int r = 0; r < 4; ++r) {
          const int q = pr + r;
          Ps[w][q * 64 + ((fn * 16 + l15) ^ ((q & 7) << 3))] = f2bn(sacc[fn][r]);
        }
    }
    __builtin_amdgcn_s_setprio(1);
    #pragma unroll
    for (int ks = 0; ks < 2; ++ks) {
      bf16x8 pa = *(const bf16x8*)&Ps[w][l15 * 64 + kf[ks]];
      #pragma unroll
      for (int fd = 0; fd < 4; ++fd) {
        bf16x8 vbf = *(const bf16x8*)&Vts[(fd * 16 + l15) * 64 + kf[ks]];
        oacc[fd] = __builtin_amdgcn_mfma_f32_16x16x32_bf16(pa, vbf, oacc[fd], 0, 0, 0);
      }
    }
    __builtin_amdgcn_s_setprio(0);
    __syncthreads();
  }

  // final row-sum reduction (once, not per tile)
  #pragma unroll
  for (int r = 0; r < 4; ++r) {
    #pragma unroll
    for (int m = 1; m <= 8; m <<= 1) lpart[r] += __shfl_xor(lpart[r], m, 64);
  }

  #pragma unroll
  for (int fd = 0; fd < 4; ++fd)
    #pragma unroll
    for (int r = 0; r < 4; ++r) {
      const int row = q0 + hi * 4 + r;
      const float v = oacc[fd][r] / lpart[r];
      O[base + (size_t)row * DM + fd * 16 + l15] = f2bn(v);
    }
}

// ---------------------------------------------------------------------------
extern "C" void kernel_launch(void* const* d_in, const int* in_sizes, int n_in,
                              void* d_out, int out_size, void* d_ws, size_t ws_size,
                              hipStream_t stream) {
  const float* x    = (const float*)d_in[0];
  const float* Wq   = (const float*)d_in[1];
  const float* bq   = (const float*)d_in[2];
  const float* Wk   = (const float*)d_in[3];
  const float* bk   = (const float*)d_in[4];
  const float* Wv   = (const float*)d_in[5];
  const float* bv   = (const float*)d_in[6];
  const float* Wo   = (const float*)d_in[7];
  const float* bo   = (const float*)d_in[8];
  const float* ln1g = (const float*)d_in[9];
  const float* ln1b = (const float*)d_in[10];
  const float* W1   = (const float*)d_in[11];
  const float* b1   = (const float*)d_in[12];
  const float* W2   = (const float*)d_in[13];
  const float* b2   = (const float*)d_in[14];
  const float* ln2g = (const float*)d_in[15];
  const float* ln2b = (const float*)d_in[16];
  float* out = (float*)d_out;

  char* wsb = (char*)d_ws;
  size_t off = 0;
  auto alloc = [&](size_t bytes) -> char* {
    char* pp = wsb + off;
    off += (bytes + 255) & ~(size_t)255;
    return pp;
  };
  u16* Wq_b = (u16*)alloc((size_t)DM * DM * 2);
  u16* Wk_b = (u16*)alloc((size_t)DM * DM * 2);
  u16* Wv_b = (u16*)alloc((size_t)DM * DM * 2);
  u16* Wo_b = (u16*)alloc((size_t)DM * DM * 2);
  u16* W1_b = (u16*)alloc((size_t)DFF * DM * 2);
  u16* W2_b = (u16*)alloc((size_t)DM * DFF * 2);
  u16* xn   = (u16*)alloc((size_t)MROWS * DM * 2);
  u16* qb   = (u16*)alloc((size_t)MROWS * DM * 2);
  u16* kb   = (u16*)alloc((size_t)MROWS * DM * 2);
  u16* vt   = (u16*)alloc((size_t)MROWS * DM * 2);  // transposed V
  u16* ao   = (u16*)alloc((size_t)MROWS * DM * 2);  // attn out, then LN2 out
  u16* h1   = (u16*)alloc((size_t)MROWS * DFF * 2);

  // K-split partial buffers (fp32, 16 MB each) reuse dead regions:
  // pA = xn∪qb, pB = kb∪vt — dead during O-proj (after attn) and FFN2.
  float* pA = (float*)xn;
  float* pB = (float*)kb;

  // 1. convert weights to bf16
  CvtArgs ca;
  ca.src[0] = Wq; ca.dst[0] = Wq_b; ca.n4[0] = DM * DM / 4;
  ca.src[1] = Wk; ca.dst[1] = Wk_b; ca.n4[1] = DM * DM / 4;
  ca.src[2] = Wv; ca.dst[2] = Wv_b; ca.n4[2] = DM * DM / 4;
  ca.src[3] = Wo; ca.dst[3] = Wo_b; ca.n4[3] = DM * DM / 4;
  ca.src[4] = W1; ca.dst[4] = W1_b; ca.n4[4] = DFF * DM / 4;
  ca.src[5] = W2; ca.dst[5] = W2_b; ca.n4[5] = DM * DFF / 4;
  cvt_kernel<<<2048, 256, 0, stream>>>(ca);

  // 2. LN1
  ln_kernel<<<MROWS, 256, 0, stream>>>(x, ln1g, ln1b, xn);

  // 3. QKV projections (z-fused; V transposed; Q pre-scaled by 1/8)
  GemmPtrs pq = {};
  pq.W[0] = Wq_b; pq.W[1] = Wk_b; pq.W[2] = Wv_b;
  pq.bias[0] = bq; pq.bias[1] = bk; pq.bias[2] = bv;
  pq.out[0] = qb; pq.out[1] = kb; pq.out[2] = vt;
  pq.vtrans = 1;
  gemm_bt<0><<<dim3(DM / 128, MROWS / 128, 3), 256, 0, stream>>>(xn, pq, MROWS, DM, DM, DM);

  // 4. attention
  attn_kernel<<<dim3(SEQ / 64, 2 * NH), 256, 0, stream>>>(qb, kb, vt, ao);

  // 5. output projection, K-split x2 -> partials; fused combine+bias+x+LN2
  GemmPtrs po = {};
  po.W[0] = Wo_b; po.W[1] = Wo_b;
  po.bias[0] = bo; po.bias[1] = bo;
  po.out[0] = pA; po.out[1] = pB;
  gemm_bt<3><<<dim3(DM / 128, MROWS / 128, 2), 256, 0, stream>>>(ao, po, MROWS, DM, DM, DM / 2);
  combine_ln_kernel<<<MROWS, 256, 0, stream>>>((const float4*)pA, (const float4*)pB,
                                               (const float4*)bo, (const float4*)x,
                                               (float4*)out, ln2g, ln2b, ao);

  // 6. FFN up + GELU (input: LN2 output in ao)
  GemmPtrs p1 = {};
  p1.W[0] = W1_b; p1.bias[0] = b1; p1.out[0] = h1;
  gemm_bt<1><<<dim3(DFF / 128, MROWS / 128, 1), 256, 0, stream>>>(ao, p1, MROWS, DFF, DM, DM);

  // 7. FFN down, K-split x2 -> partials, then combine(+bias+resid in place)
  GemmPtrs p2 = {};
  p2.W[0] = W2_b; p2.W[1] = W2_b;
  p2.bias[0] = b2; p2.bias[1] = b2;
  p2.out[0] = pA; p2.out[1] = pB;
  gemm_bt<3><<<dim3(DM / 128, MROWS / 128, 2), 256, 0, stream>>>(h1, p2, MROWS, DM, DFF, DFF / 2);
  combine_kernel<<<2048, 256, 0, stream>>>((const float4*)pA, (const float4*)pB,
                                           (const float4*)b2, (const float4*)out,
                                           (float4*)out, MROWS * DM / 4, DM / 4 - 1);
}

// Round 7
// 317.051 us; speedup vs baseline: 1.1408x; 1.0004x over previous
//
#include <hip/hip_runtime.h>
#include <hip/hip_bf16.h>
#include <stdint.h>

#define DM 1024
#define DFF 4096
#define NH 16
#define DH 64
#define SEQ 2048
#define MROWS 4096  // B*S

typedef unsigned short u16;
typedef __attribute__((ext_vector_type(8))) short bf16x8;
typedef __attribute__((ext_vector_type(4))) float f32x4;
typedef __attribute__((ext_vector_type(16))) float f32x16;
typedef __attribute__((ext_vector_type(4))) unsigned short u16x4;

__device__ __forceinline__ u16 f2b(float f) {
  union { float f; uint32_t u; } v; v.f = f;
  uint32_t r = v.u + 0x7FFFu + ((v.u >> 16) & 1u);
  return (u16)(r >> 16);
}

// native convert — clang emits v_cvt_pk_bf16_f32 for pairs (RNE)
__device__ __forceinline__ u16 f2bn(float f) {
  __hip_bfloat16 h = __float2bfloat16(f);
  return *reinterpret_cast<u16*>(&h);
}

__device__ __forceinline__ uint32_t pk2(float lo, float hi) {
  return (uint32_t)f2bn(lo) | ((uint32_t)f2bn(hi) << 16);
}

__device__ __forceinline__ void gl_lds16(const void* g, void* l) {
  __builtin_amdgcn_global_load_lds(
      (const __attribute__((address_space(1))) uint32_t*)g,
      (__attribute__((address_space(3))) uint32_t*)l, 16, 0, 0);
}

// ---------------- weight fp32 -> bf16 convert (all 6 weights, one kernel) --
struct CvtArgs { const float* src[6]; u16* dst[6]; int n4[6]; };

__global__ void cvt_kernel(CvtArgs a) {
  const int stride = gridDim.x * blockDim.x;
  const int t0 = blockIdx.x * blockDim.x + threadIdx.x;
  for (int i = 0; i < 6; ++i) {
    const float4* s = (const float4*)a.src[i];
    u16x4* d = (u16x4*)a.dst[i];
    const int n = a.n4[i];
    for (int idx = t0; idx < n; idx += stride) {
      float4 v = s[idx];
      u16x4 o;
      o[0] = f2b(v.x); o[1] = f2b(v.y); o[2] = f2b(v.z); o[3] = f2b(v.w);
      d[idx] = o;
    }
  }
}

// ---------------- fused LayerNorm: fp32 in -> bf16 out ---------------------
__global__ __launch_bounds__(256)
void ln_kernel(const float* __restrict__ x, const float* __restrict__ g,
               const float* __restrict__ be, u16* __restrict__ out) {
  const int row = blockIdx.x;
  const int tid = threadIdx.x;
  const float4 v = ((const float4*)(x + (size_t)row * DM))[tid];
  float s  = v.x + v.y + v.z + v.w;
  float s2 = v.x * v.x + v.y * v.y + v.z * v.z + v.w * v.w;
  #pragma unroll
  for (int m = 1; m < 64; m <<= 1) {
    s  += __shfl_xor(s,  m, 64);
    s2 += __shfl_xor(s2, m, 64);
  }
  __shared__ float red[8];
  const int w = tid >> 6, lane = tid & 63;
  if (lane == 0) { red[w] = s; red[4 + w] = s2; }
  __syncthreads();
  s  = red[0] + red[1] + red[2] + red[3];
  s2 = red[4] + red[5] + red[6] + red[7];
  const float mu  = s * (1.0f / DM);
  const float var = s2 * (1.0f / DM) - mu * mu;
  const float rstd = rsqrtf(var + 1e-5f);
  const float4 gv = ((const float4*)g)[tid];
  const float4 bv = ((const float4*)be)[tid];
  u16x4 o;
  o[0] = f2b((v.x - mu) * rstd * gv.x + bv.x);
  o[1] = f2b((v.y - mu) * rstd * gv.y + bv.y);
  o[2] = f2b((v.z - mu) * rstd * gv.z + bv.z);
  o[3] = f2b((v.w - mu) * rstd * gv.w + bv.w);
  ((u16x4*)(out + (size_t)row * DM))[tid] = o;
}

// ---------------- combine: out = p0 + p1 + bias + resid (fp32) -------------
__global__ __launch_bounds__(256)
void combine_kernel(const float4* __restrict__ p0, const float4* __restrict__ p1,
                    const float4* __restrict__ bias, const float4* __restrict__ resid,
                    float4* __restrict__ out, int total4, int colmask4) {
  for (int i = blockIdx.x * 256 + threadIdx.x; i < total4; i += gridDim.x * 256) {
    float4 a = p0[i], b = p1[i], bs = bias[i & colmask4], rr = resid[i];
    float4 o;
    o.x = a.x + b.x + bs.x + rr.x;
    o.y = a.y + b.y + bs.y + rr.y;
    o.z = a.z + b.z + bs.z + rr.z;
    o.w = a.w + b.w + bs.w + rr.w;
    out[i] = o;
  }
}

// ------- fused combine + LayerNorm: x1 = p0+p1+bias+resid (fp32 out),
//         norm = LN(x1)*g+b (bf16 out, separate buffer) ---------------------
__global__ __launch_bounds__(256)
void combine_ln_kernel(const float4* __restrict__ p0, const float4* __restrict__ p1,
                       const float4* __restrict__ bias, const float4* __restrict__ resid,
                       float4* __restrict__ xout,
                       const float* __restrict__ g, const float* __restrict__ be,
                       u16* __restrict__ nout) {
  const int row = blockIdx.x;
  const int tid = threadIdx.x;
  const int i = row * (DM / 4) + tid;
  const float4 a = p0[i], b = p1[i], bs = bias[tid], rr = resid[i];
  float4 v;
  v.x = a.x + b.x + bs.x + rr.x;
  v.y = a.y + b.y + bs.y + rr.y;
  v.z = a.z + b.z + bs.z + rr.z;
  v.w = a.w + b.w + bs.w + rr.w;
  xout[i] = v;
  float s  = v.x + v.y + v.z + v.w;
  float s2 = v.x * v.x + v.y * v.y + v.z * v.z + v.w * v.w;
  #pragma unroll
  for (int m = 1; m < 64; m <<= 1) {
    s  += __shfl_xor(s,  m, 64);
    s2 += __shfl_xor(s2, m, 64);
  }
  __shared__ float red[8];
  const int w = tid >> 6, lane = tid & 63;
  if (lane == 0) { red[w] = s; red[4 + w] = s2; }
  __syncthreads();
  s  = red[0] + red[1] + red[2] + red[3];
  s2 = red[4] + red[5] + red[6] + red[7];
  const float mu  = s * (1.0f / DM);
  const float var = s2 * (1.0f / DM) - mu * mu;
  const float rstd = rsqrtf(var + 1e-5f);
  const float4 gv = ((const float4*)g)[tid];
  const float4 bv = ((const float4*)be)[tid];
  u16x4 o;
  o[0] = f2b((v.x - mu) * rstd * gv.x + bv.x);
  o[1] = f2b((v.y - mu) * rstd * gv.y + bv.y);
  o[2] = f2b((v.z - mu) * rstd * gv.z + bv.z);
  o[3] = f2b((v.w - mu) * rstd * gv.w + bv.w);
  ((u16x4*)(nout + (size_t)row * DM))[tid] = o;
}

// ---------------- GEMM: C[M,N] = A[M,K](bf16) * W[N,K](bf16)^T + bias ------
// EPI 0: -> bf16 (z==2 + vtrans: write transposed [b*DM+col][SEQ];
//                 z==0 + vtrans: scale by 1/8 — Q head-dim scale folded in)
// EPI 1: +GELU(exact) -> bf16      EPI 2: +resid -> f32
// EPI 3: K-split partial, no bias -> f32 (z selects K-chunk + partial buffer)
struct GemmPtrs { const u16* W[3]; const float* bias[3]; void* out[3];
                  const float* resid; int vtrans; };

template<int EPI>
__global__ __launch_bounds__(256)
void gemm_bt(const u16* __restrict__ A, GemmPtrs p, int M, int N,
             int Kstride, int Kchunk) {
  __shared__ __align__(16) u16 As[128 * 64];
  __shared__ __align__(16) u16 Bs[128 * 64];
  const u16* __restrict__ Wm = p.W[blockIdx.z];
  const float* __restrict__ bias = p.bias[blockIdx.z];
  void* outv = p.out[blockIdx.z];
  const float* resid = p.resid;

  const int tid = threadIdx.x;
  const int lane = tid & 63;
  const int w = tid >> 6;
  const int brow = blockIdx.y * 128;
  const int bcol = blockIdx.x * 128;
  const int wr = (w >> 1) * 64, wc = (w & 1) * 64;
  const int koff = (EPI == 3) ? blockIdx.z * Kchunk : 0;

  f32x4 acc[4][4] = {};

  const int srow = lane >> 3;           // staging row within 8-row group
  const int scol = (lane & 7) * 8;      // staging col (bf16 elements)
  const int nkt = Kchunk >> 6;
  for (int kt = 0; kt < nkt; ++kt) {
    const int k0 = koff + kt * 64;
    #pragma unroll
    for (int i = 0; i < 4; ++i) {
      const int r = i * 32 + w * 8;
      gl_lds16(&A [(size_t)(brow + r + srow) * Kstride + k0 + scol], &As[r * 64]);
      gl_lds16(&Wm[(size_t)(bcol + r + srow) * Kstride + k0 + scol], &Bs[r * 64]);
    }
    __syncthreads();
    #pragma unroll
    for (int ks = 0; ks < 2; ++ks) {
      const int ko = ks * 32 + (lane >> 4) * 8;
      bf16x8 a[4], b[4];
      #pragma unroll
      for (int f = 0; f < 4; ++f)
        a[f] = *(const bf16x8*)&As[(wr + f * 16 + (lane & 15)) * 64 + ko];
      #pragma unroll
      for (int f = 0; f < 4; ++f)
        b[f] = *(const bf16x8*)&Bs[(wc + f * 16 + (lane & 15)) * 64 + ko];
      #pragma unroll
      for (int fr = 0; fr < 4; ++fr)
        #pragma unroll
        for (int fc = 0; fc < 4; ++fc)
          acc[fr][fc] = __builtin_amdgcn_mfma_f32_16x16x32_bf16(a[fr], b[fc], acc[fr][fc], 0, 0, 0);
    }
    __syncthreads();
  }

  const int orow0 = brow + wr + (lane >> 4) * 4;
  const int ocol0 = bcol + wc + (lane & 15);

  if (EPI == 0 && p.vtrans && blockIdx.z == 2) {
    // V projection written transposed: Vt[(b*DM + col)][s], s = row % SEQ
    #pragma unroll
    for (int fr = 0; fr < 4; ++fr) {
      const int row0 = orow0 + fr * 16;
      const int bq = row0 >> 11, s0 = row0 & (SEQ - 1);
      #pragma unroll
      for (int fc = 0; fc < 4; ++fc) {
        const int col = ocol0 + fc * 16;
        const float bvv = bias[col];
        u16x4 o;
        #pragma unroll
        for (int r = 0; r < 4; ++r) o[r] = f2b(acc[fr][fc][r] + bvv);
        *(u16x4*)((u16*)outv + (size_t)(bq * DM + col) * SEQ + s0) = o;
      }
    }
    return;
  }

  const float oscale = (EPI == 0 && p.vtrans && blockIdx.z == 0) ? 0.125f : 1.0f;

  #pragma unroll
  for (int fr = 0; fr < 4; ++fr) {
    #pragma unroll
    for (int fc = 0; fc < 4; ++fc) {
      const int col = ocol0 + fc * 16;
      const float bvv = (EPI == 3) ? 0.0f : bias[col];
      #pragma unroll
      for (int r = 0; r < 4; ++r) {
        const int row = orow0 + fr * 16 + r;
        const size_t idx = (size_t)row * N + col;
        float v = acc[fr][fc][r] + bvv;
        if (EPI == 0) {
          ((u16*)outv)[idx] = f2b(v * oscale);
        } else if (EPI == 1) {
          float ge = 0.5f * v * (1.0f + erff(v * 0.70710678118654752f));
          ((u16*)outv)[idx] = f2b(ge);
        } else if (EPI == 2) {
          ((float*)outv)[idx] = v + resid[idx];
        } else {
          ((float*)outv)[idx] = v;   // partial, bias added in combine
        }
      }
    }
  }
}

// ---------------- flash attention, 32x32 swapped-QK^T, in-register softmax -
// Q,K [B,S,H*DH] (Q pre-scaled 1/8); Vt [(b*DM+h*DH+d)][s]; O [B,S,H*DH].
// 2 waves x 32 q-rows per block. S^T = mfma32(K, Q): lane owns q = lane&31
// (cols); rows k = crow(r,hi) = (r&3)+8*(r>>2)+4*hi (m74/m101-verified C
// layout). Softmax entirely in registers; P->bf16 packed via paired casts
// (v_cvt_pk) + shfl_xor(32) half-exchange into PV A-fragments. Defer-max
// (THR=8): rescale redistributes per-q factor via 16 bpermutes, rare.
// LDS: K + Vt tiles only (16 KB), XOR-swizzled (rule #21 both-sides).
__global__ __launch_bounds__(128, 4)
void attn_kernel(const u16* __restrict__ Q, const u16* __restrict__ K,
                 const u16* __restrict__ Vt, u16* __restrict__ O) {
  __shared__ __align__(16) u16 Ks[64 * 64];    // [k][d]
  __shared__ __align__(16) u16 Vts[64 * 64];   // [d][k]
  const int tid = threadIdx.x, lane = tid & 63, w = tid >> 6;
  const int bh = blockIdx.y, b = bh >> 4, h = bh & 15;
  const int q0 = blockIdx.x * 64 + w * 32;     // wave's q base
  const size_t base = (size_t)b * SEQ * DM + (size_t)h * DH;
  const size_t vbase = (size_t)(b * DM + h * DH) * SEQ;

  const int l31 = lane & 31, hi = lane >> 5, l7 = l31 & 7;

  // Q fragments (B-operand): col=q=l31, k(d) = dt*16 + hi*8 + j
  bf16x8 qf[4];
  {
    const size_t qrow = base + (size_t)(q0 + l31) * DM;
    #pragma unroll
    for (int dt = 0; dt < 4; ++dt)
      qf[dt] = *(const bf16x8*)&Q[qrow + dt * 16 + hi * 8];
  }

  f32x16 oacc[2] = {};   // d-tiles 0-31, 32-63
  float mq = -1e30f, lq = 0.0f;   // for q = q0 + l31 (column layout)

  for (int kt = 0; kt < SEQ / 64; ++kt) {
    // stage K[64k][64d] and Vt[64d][64k], swizzled chunk = c ^ (row&7)
    #pragma unroll
    for (int i = 0; i < 4; ++i) {
      const int r0 = w * 32 + i * 8;            // wave-uniform LDS base row
      const int row = r0 + (lane >> 3);
      const int ch = ((lane & 7) ^ (row & 7)) * 8;
      gl_lds16(&K[base + (size_t)(kt * 64 + row) * DM + ch], &Ks[r0 * 64]);
      gl_lds16(&Vt[vbase + (size_t)row * SEQ + kt * 64 + ch], &Vts[r0 * 64]);
    }
    __syncthreads();

    #pragma unroll
    for (int sub = 0; sub < 2; ++sub) {         // 32-key sub-blocks
      // S^T = sum_dt mfma32(Kfrag, Qfrag)
      f32x16 sacc = {};
      __builtin_amdgcn_s_setprio(1);
      #pragma unroll
      for (int dt = 0; dt < 4; ++dt) {
        bf16x8 kf = *(const bf16x8*)&Ks[(sub * 32 + l31) * 64 + (((dt << 1) | hi) ^ l7) * 8];
        sacc = __builtin_amdgcn_mfma_f32_32x32x16_bf16(kf, qf[dt], sacc, 0, 0, 0);
      }
      __builtin_amdgcn_s_setprio(0);

      // column max for q = l31 (16 in-lane + cross-half exchange)
      float tm = sacc[0];
      #pragma unroll
      for (int r = 1; r < 16; ++r) tm = fmaxf(tm, sacc[r]);
      tm = fmaxf(tm, __shfl_xor(tm, 32, 64));

      if (__any(tm > mq + 8.0f)) {
        const float mnew = fmaxf(mq, tm);
        const float fs = __expf(mq - mnew);
        mq = mnew;
        lq *= fs;
        #pragma unroll
        for (int r = 0; r < 16; ++r) {
          const float fsr = __shfl(fs, (r & 3) + 8 * (r >> 2) + 4 * hi, 64);
          oacc[0][r] *= fsr;
          oacc[1][r] *= fsr;
        }
      }

      // exp + pack into PV A-fragments (two k-slots of 16)
      uint32_t wd[2][4];
      float ps = 0.0f;
      #pragma unroll
      for (int half = 0; half < 2; ++half) {
        float p[8];
        #pragma unroll
        for (int j = 0; j < 8; ++j) {
          p[j] = __expf(sacc[half * 8 + j] - mq);
          ps += p[j];
        }
        const uint32_t a = pk2(p[0], p[1]), c = pk2(p[2], p[3]);
        const uint32_t bb = pk2(p[4], p[5]), d = pk2(p[6], p[7]);
        const uint32_t xa = (uint32_t)__shfl_xor((int)a, 32, 64);
        const uint32_t xb = (uint32_t)__shfl_xor((int)bb, 32, 64);
        const uint32_t xc = (uint32_t)__shfl_xor((int)c, 32, 64);
        const uint32_t xd = (uint32_t)__shfl_xor((int)d, 32, 64);
        wd[half][0] = hi ? xb : a;
        wd[half][1] = hi ? xd : c;
        wd[half][2] = hi ? bb : xa;
        wd[half][3] = hi ? d : xc;
      }
      lq += ps;
      bf16x8 pa0, pa1;
      #pragma unroll
      for (int j = 0; j < 4; ++j) {
        ((uint32_t*)&pa0)[j] = wd[0][j];
        ((uint32_t*)&pa1)[j] = wd[1][j];
      }

      // PV: oacc[dt] += pa[ks] * V[ks][dt]
      __builtin_amdgcn_s_setprio(1);
      #pragma unroll
      for (int dt = 0; dt < 2; ++dt) {
        #pragma unroll
        for (int ks = 0; ks < 2; ++ks) {
          bf16x8 vf = *(const bf16x8*)&Vts[(dt * 32 + l31) * 64 +
                                           (((sub << 2) | (ks << 1) | hi) ^ l7) * 8];
          oacc[dt] = __builtin_amdgcn_mfma_f32_32x32x16_bf16(ks ? pa1 : pa0, vf, oacc[dt], 0, 0, 0);
        }
      }
      __builtin_amdgcn_s_setprio(0);
    }
    __syncthreads();
  }

  // final: total row sum, redistribute to output-row layout, write O
  const float ltot = lq + __shfl_xor(lq, 32, 64);
  #pragma unroll
  for (int r = 0; r < 16; ++r) {
    const int crow = (r & 3) + 8 * (r >> 2) + 4 * hi;
    const float lr = __shfl(ltot, crow, 64);
    const float inv = 1.0f / lr;
    const size_t orow = base + (size_t)(q0 + crow) * DM;
    O[orow + l31]      = f2bn(oacc[0][r] * inv);
    O[orow + 32 + l31] = f2bn(oacc[1][r] * inv);
  }
}

// ---------------------------------------------------------------------------
extern "C" void kernel_launch(void* const* d_in, const int* in_sizes, int n_in,
                              void* d_out, int out_size, void* d_ws, size_t ws_size,
                              hipStream_t stream) {
  const float* x    = (const float*)d_in[0];
  const float* Wq   = (const float*)d_in[1];
  const float* bq   = (const float*)d_in[2];
  const float* Wk   = (const float*)d_in[3];
  const float* bk   = (const float*)d_in[4];
  const float* Wv   = (const float*)d_in[5];
  const float* bv   = (const float*)d_in[6];
  const float* Wo   = (const float*)d_in[7];
  const float* bo   = (const float*)d_in[8];
  const float* ln1g = (const float*)d_in[9];
  const float* ln1b = (const float*)d_in[10];
  const float* W1   = (const float*)d_in[11];
  const float* b1   = (const float*)d_in[12];
  const float* W2   = (const float*)d_in[13];
  const float* b2   = (const float*)d_in[14];
  const float* ln2g = (const float*)d_in[15];
  const float* ln2b = (const float*)d_in[16];
  float* out = (float*)d_out;

  char* wsb = (char*)d_ws;
  size_t off = 0;
  auto alloc = [&](size_t bytes) -> char* {
    char* pp = wsb + off;
    off += (bytes + 255) & ~(size_t)255;
    return pp;
  };
  u16* Wq_b = (u16*)alloc((size_t)DM * DM * 2);
  u16* Wk_b = (u16*)alloc((size_t)DM * DM * 2);
  u16* Wv_b = (u16*)alloc((size_t)DM * DM * 2);
  u16* Wo_b = (u16*)alloc((size_t)DM * DM * 2);
  u16* W1_b = (u16*)alloc((size_t)DFF * DM * 2);
  u16* W2_b = (u16*)alloc((size_t)DM * DFF * 2);
  u16* xn   = (u16*)alloc((size_t)MROWS * DM * 2);
  u16* qb   = (u16*)alloc((size_t)MROWS * DM * 2);
  u16* kb   = (u16*)alloc((size_t)MROWS * DM * 2);
  u16* vt   = (u16*)alloc((size_t)MROWS * DM * 2);  // transposed V
  u16* ao   = (u16*)alloc((size_t)MROWS * DM * 2);  // attn out, then LN2 out
  u16* h1   = (u16*)alloc((size_t)MROWS * DFF * 2);

  // K-split partial buffers (fp32, 16 MB each) reuse dead regions:
  // pA = xn∪qb, pB = kb∪vt — dead during O-proj (after attn) and FFN2.
  float* pA = (float*)xn;
  float* pB = (float*)kb;

  // 1. convert weights to bf16
  CvtArgs ca;
  ca.src[0] = Wq; ca.dst[0] = Wq_b; ca.n4[0] = DM * DM / 4;
  ca.src[1] = Wk; ca.dst[1] = Wk_b; ca.n4[1] = DM * DM / 4;
  ca.src[2] = Wv; ca.dst[2] = Wv_b; ca.n4[2] = DM * DM / 4;
  ca.src[3] = Wo; ca.dst[3] = Wo_b; ca.n4[3] = DM * DM / 4;
  ca.src[4] = W1; ca.dst[4] = W1_b; ca.n4[4] = DFF * DM / 4;
  ca.src[5] = W2; ca.dst[5] = W2_b; ca.n4[5] = DM * DFF / 4;
  cvt_kernel<<<2048, 256, 0, stream>>>(ca);

  // 2. LN1
  ln_kernel<<<MROWS, 256, 0, stream>>>(x, ln1g, ln1b, xn);

  // 3. QKV projections (z-fused; V transposed; Q pre-scaled by 1/8)
  GemmPtrs pq = {};
  pq.W[0] = Wq_b; pq.W[1] = Wk_b; pq.W[2] = Wv_b;
  pq.bias[0] = bq; pq.bias[1] = bk; pq.bias[2] = bv;
  pq.out[0] = qb; pq.out[1] = kb; pq.out[2] = vt;
  pq.vtrans = 1;
  gemm_bt<0><<<dim3(DM / 128, MROWS / 128, 3), 256, 0, stream>>>(xn, pq, MROWS, DM, DM, DM);

  // 4. attention (128-thread blocks, 2 waves x 32 q)
  attn_kernel<<<dim3(SEQ / 64, 2 * NH), 128, 0, stream>>>(qb, kb, vt, ao);

  // 5. output projection, K-split x2 -> partials; fused combine+bias+x+LN2
  GemmPtrs po = {};
  po.W[0] = Wo_b; po.W[1] = Wo_b;
  po.bias[0] = bo; po.bias[1] = bo;
  po.out[0] = pA; po.out[1] = pB;
  gemm_bt<3><<<dim3(DM / 128, MROWS / 128, 2), 256, 0, stream>>>(ao, po, MROWS, DM, DM, DM / 2);
  combine_ln_kernel<<<MROWS, 256, 0, stream>>>((const float4*)pA, (const float4*)pB,
                                               (const float4*)bo, (const float4*)x,
                                               (float4*)out, ln2g, ln2b, ao);

  // 6. FFN up + GELU (input: LN2 output in ao)
  GemmPtrs p1 = {};
  p1.W[0] = W1_b; p1.bias[0] = b1; p1.out[0] = h1;
  gemm_bt<1><<<dim3(DFF / 128, MROWS / 128, 1), 256, 0, stream>>>(ao, p1, MROWS, DFF, DM, DM);

  // 7. FFN down, K-split x2 -> partials, then combine(+bias+resid in place)
  GemmPtrs p2 = {};
  p2.W[0] = W2_b; p2.W[1] = W2_b;
  p2.bias[0] = b2; p2.bias[1] = b2;
  p2.out[0] = pA; p2.out[1] = pB;
  gemm_bt<3><<<dim3(DM / 128, MROWS / 128, 2), 256, 0, stream>>>(h1, p2, MROWS, DM, DFF, DFF / 2);
  combine_kernel<<<2048, 256, 0, stream>>>((const float4*)pA, (const float4*)pB,
                                           (const float4*)b2, (const float4*)out,
                                           (float4*)out, MROWS * DM / 4, DM / 4 - 1);
}